// Round 1
// baseline (12711.517 us; speedup 1.0000x reference)
//
#include <hip/hip_runtime.h>
#include <math.h>

#define T_STEPS 1024
#define I_DIM   128
#define H_DIM   512
#define O_DIM   512
#define M_PAT   32768
#define SCAN_WGS 8

// ---------------------------------------------------------------------------
// K0: xw[t][j] = inp[t,:] . W_ih[j,:] + b_ih[j] + b_hh[j]
// ---------------------------------------------------------------------------
__global__ __launch_bounds__(256) void xw_kernel(const float* __restrict__ inp,
    const float* __restrict__ W_ih, const float* __restrict__ b_ih,
    const float* __restrict__ b_hh, float* __restrict__ xw) {
  int t = blockIdx.x;
  __shared__ float4 xs4[I_DIM / 4];
  if (threadIdx.x < I_DIM / 4)
    xs4[threadIdx.x] = ((const float4*)(inp + (size_t)t * I_DIM))[threadIdx.x];
  __syncthreads();
  for (int j = threadIdx.x; j < H_DIM; j += 256) {
    const float4* w4 = (const float4*)(W_ih + (size_t)j * I_DIM);
    float acc = 0.f;
#pragma unroll
    for (int i = 0; i < I_DIM / 4; i++) {
      float4 w = w4[i]; float4 x = xs4[i];
      acc += w.x * x.x + w.y * x.y + w.z * x.z + w.w * x.w;
    }
    xw[(size_t)t * H_DIM + j] = acc + b_ih[j] + b_hh[j];
  }
}

// ---------------------------------------------------------------------------
// K1: RNN scan. 8 WGs x 256 threads; WG w owns rows [64w, 64w+64).
// Weights held in VGPRs (128 regs/lane). Cross-WG sync: per-step flag,
// release atomicAdd by producer wave, acquire-spin by tid0, h broadcast
// through g_cur (global).
// ---------------------------------------------------------------------------
__global__ __launch_bounds__(256, 1) void scan_kernel(
    const float* __restrict__ W_hh, const float* __restrict__ xw,
    const float* __restrict__ h0, float* __restrict__ g_cur,
    float* __restrict__ h_last, unsigned* __restrict__ flags) {
  const int wg   = blockIdx.x;           // 0..7
  const int lane = threadIdx.x & 63;     // local row
  const int part = threadIdx.x >> 6;     // k-chunk 0..3 (128 cols each)
  const int row  = wg * 64 + lane;

  float4 w[32];
  const float4* wsrc = (const float4*)(W_hh + (size_t)row * H_DIM + part * 128);
#pragma unroll
  for (int i = 0; i < 32; i++) w[i] = wsrc[i];

  __shared__ float4 h_s[H_DIM / 4];
  __shared__ float  red[4][64];

  for (int t = 0; t < T_STEPS; t++) {
    if (threadIdx.x == 0 && t > 0) {
      while (__hip_atomic_load(flags + (t - 1), __ATOMIC_ACQUIRE,
                               __HIP_MEMORY_SCOPE_AGENT) < SCAN_WGS) {
        __builtin_amdgcn_s_sleep(1);
      }
    }
    __syncthreads();
    const float4* hsrc = (t == 0) ? (const float4*)h0
                                  : (const float4*)(g_cur + (size_t)(t - 1) * H_DIM);
    if (threadIdx.x < H_DIM / 4) h_s[threadIdx.x] = hsrc[threadIdx.x];
    __syncthreads();

    float acc = 0.f;
#pragma unroll
    for (int i = 0; i < 32; i++) {
      float4 h4 = h_s[part * 32 + i];  // wave-uniform address -> broadcast
      acc += h4.x * w[i].x + h4.y * w[i].y + h4.z * w[i].z + h4.w * w[i].w;
    }
    red[part][lane] = acc;
    __syncthreads();

    if (part == 0) {
      float pre = red[0][lane] + red[1][lane] + red[2][lane] + red[3][lane]
                + xw[(size_t)t * H_DIM + row];
      float h = tanhf(pre);
      g_cur[(size_t)t * H_DIM + row] = h;
      if (t == T_STEPS - 1) h_last[row] = h;
      __threadfence();
      if (lane == 0)
        __hip_atomic_fetch_add(flags + t, 1u, __ATOMIC_RELEASE,
                               __HIP_MEMORY_SCOPE_AGENT);
    }
  }
}

// ---------------------------------------------------------------------------
// K2: key norms. bkx[m] = 8*sum(x_vals[m]^2), bkg[m] = 8*sum(g_keys[m]^2)
// ---------------------------------------------------------------------------
__global__ __launch_bounds__(256) void norms_kernel(const float* __restrict__ patterns,
    float* __restrict__ bkx, float* __restrict__ bkg) {
  int lane = threadIdx.x & 63;
  int m = blockIdx.x * 4 + (threadIdx.x >> 6);
  const float4* row = (const float4*)(patterns + (size_t)m * (O_DIM + H_DIM));
  float ax = 0.f, ag = 0.f;
#pragma unroll
  for (int jj = 0; jj < 4; jj++) {
    float4 v = row[lane + 64 * jj];
    float s = v.x * v.x + v.y * v.y + v.z * v.z + v.w * v.w;
    if (jj < 2) ax += s; else ag += s;
  }
#pragma unroll
  for (int off = 1; off < 64; off <<= 1) {
    ax += __shfl_xor(ax, off, 64);
    ag += __shfl_xor(ag, off, 64);
  }
  if (lane == 0) { bkx[m] = 8.f * ax; bkg[m] = 8.f * ag; }
}

// ---------------------------------------------------------------------------
// K3: flash retrieval. logits = 16*(q.k) - 8*||k||^2 ; online softmax over
// the WG's key chunk; partial (m,l,acc) to ws. Tq=32 queries/WG, Bk=16.
// LDS layout XOR-swizzled: phys_f4 = f4 ^ ((f4>>3)&7) -> <=2-way bank alias.
// ---------------------------------------------------------------------------
__global__ __launch_bounds__(256, 2) void flash_kernel(
    const float* __restrict__ Qg, const float* __restrict__ Qx,
    const float* __restrict__ patterns,
    const float* __restrict__ bkx, const float* __restrict__ bkg,
    float* __restrict__ pacc, float* __restrict__ pml, int S) {
  int b = blockIdx.x;
  int sidx = b % S;
  int qt   = (b / S) & 31;
  int ret  = b / (S * 32);

  const float* Q   = ret ? Qx : Qg;
  const float* K   = ret ? patterns : patterns + O_DIM;  // g_keys = cols [512,1024)
  const float* V   = patterns;                            // x_vals = cols [0,512)
  const float* bkk = ret ? bkx : bkg;

  const int chunk = M_PAT / S;
  const int kbeg = sidx * chunk, kend = kbeg + chunk;

  const int c  = threadIdx.x & 15;   // 32-float col chunk
  const int rp = threadIdx.x >> 4;   // row pair
  const int r0 = qt * 32 + rp * 2;

  __shared__ float4 k_s[16 * 128];
  __shared__ float4 v_s[16 * 128];

  float4 q0[8], q1[8], a0[8], a1[8];
  const float4* Q4 = (const float4*)Q;
#pragma unroll
  for (int jj = 0; jj < 8; jj++) {
    q0[jj] = Q4[(size_t)r0 * 128 + c * 8 + jj];
    q1[jj] = Q4[(size_t)(r0 + 1) * 128 + c * 8 + jj];
    a0[jj] = make_float4(0.f, 0.f, 0.f, 0.f);
    a1[jj] = make_float4(0.f, 0.f, 0.f, 0.f);
  }
  float m0 = -INFINITY, m1 = -INFINITY, l0 = 0.f, l1 = 0.f;

  for (int k0 = kbeg; k0 < kend; k0 += 16) {
    __syncthreads();
#pragma unroll
    for (int jj = 0; jj < 8; jj++) {
      int f = threadIdx.x + 256 * jj;
      int key = f >> 7, q4i = f & 127;
      int phys = q4i ^ ((q4i >> 3) & 7);
      k_s[key * 128 + phys] = ((const float4*)(K + (size_t)(k0 + key) * 1024))[q4i];
      v_s[key * 128 + phys] = ((const float4*)(V + (size_t)(k0 + key) * 1024))[q4i];
    }
    __syncthreads();

    float bk[16];
#pragma unroll
    for (int j = 0; j < 16; j++) bk[j] = bkk[k0 + j];

    float s0[16], s1[16];
    float mt0 = -INFINITY, mt1 = -INFINITY;
#pragma unroll
    for (int j = 0; j < 16; j++) {
      float d0 = 0.f, d1 = 0.f;
#pragma unroll
      for (int jj = 0; jj < 8; jj++) {
        int phys = (c * 8 + jj) ^ (c & 7);
        float4 kv = k_s[j * 128 + phys];
        d0 += q0[jj].x * kv.x + q0[jj].y * kv.y + q0[jj].z * kv.z + q0[jj].w * kv.w;
        d1 += q1[jj].x * kv.x + q1[jj].y * kv.y + q1[jj].z * kv.z + q1[jj].w * kv.w;
      }
#pragma unroll
      for (int off = 1; off < 16; off <<= 1) {
        d0 += __shfl_xor(d0, off, 16);
        d1 += __shfl_xor(d1, off, 16);
      }
      s0[j] = 16.f * d0 - bk[j];
      s1[j] = 16.f * d1 - bk[j];
      mt0 = fmaxf(mt0, s0[j]);
      mt1 = fmaxf(mt1, s1[j]);
    }

    float mn0 = fmaxf(m0, mt0), mn1 = fmaxf(m1, mt1);
    float al0 = __expf(m0 - mn0), al1 = __expf(m1 - mn1);
    l0 *= al0; l1 *= al1;
#pragma unroll
    for (int jj = 0; jj < 8; jj++) {
      a0[jj].x *= al0; a0[jj].y *= al0; a0[jj].z *= al0; a0[jj].w *= al0;
      a1[jj].x *= al1; a1[jj].y *= al1; a1[jj].z *= al1; a1[jj].w *= al1;
    }
#pragma unroll
    for (int j = 0; j < 16; j++) {
      float w0 = __expf(s0[j] - mn0), w1 = __expf(s1[j] - mn1);
      l0 += w0; l1 += w1;
#pragma unroll
      for (int jj = 0; jj < 8; jj++) {
        int phys = (c * 8 + jj) ^ (c & 7);
        float4 vv = v_s[j * 128 + phys];
        a0[jj].x += w0 * vv.x; a0[jj].y += w0 * vv.y; a0[jj].z += w0 * vv.z; a0[jj].w += w0 * vv.w;
        a1[jj].x += w1 * vv.x; a1[jj].y += w1 * vv.y; a1[jj].z += w1 * vv.z; a1[jj].w += w1 * vv.w;
      }
    }
    m0 = mn0; m1 = mn1;
  }

  size_t base4 = (((size_t)(ret * S + sidx) * T_STEPS + r0) * 512) / 4;
#pragma unroll
  for (int jj = 0; jj < 8; jj++) {
    ((float4*)pacc)[base4 + c * 8 + jj]        = a0[jj];
    ((float4*)pacc)[base4 + 128 + c * 8 + jj]  = a1[jj];
  }
  if (c == 0) {
    size_t mb = ((size_t)(ret * S + sidx) * T_STEPS + r0) * 2;
    pml[mb]     = m0; pml[mb + 1] = l0;
    pml[mb + 2] = m1; pml[mb + 3] = l1;
  }
}

// ---------------------------------------------------------------------------
// K4: combine key-split partials -> prob_g / prob_x
// ---------------------------------------------------------------------------
__global__ __launch_bounds__(256) void combine_kernel(
    const float* __restrict__ pacc, const float* __restrict__ pml,
    float* __restrict__ out, int S) {
  int b = blockIdx.x;              // ret*1024 + r
  int ret = b >> 10, r = b & 1023;
  float M = -INFINITY;
  for (int s = 0; s < S; s++)
    M = fmaxf(M, pml[((size_t)(ret * S + s) * T_STEPS + r) * 2]);
  float L = 0.f;
  for (int s = 0; s < S; s++) {
    size_t mb = ((size_t)(ret * S + s) * T_STEPS + r) * 2;
    L += pml[mb + 1] * __expf(pml[mb] - M);
  }
  float inv = 1.0f / L;
  for (int cc = threadIdx.x; cc < 512; cc += 256) {
    float acc = 0.f;
    for (int s = 0; s < S; s++) {
      size_t mb = ((size_t)(ret * S + s) * T_STEPS + r) * 2;
      float sc = __expf(pml[mb] - M);
      acc += sc * pacc[((size_t)(ret * S + s) * T_STEPS + r) * 512 + cc];
    }
    out[(size_t)ret * (T_STEPS * O_DIM) + (size_t)r * 512 + cc] = acc * inv;
  }
}

// ---------------------------------------------------------------------------
extern "C" void kernel_launch(void* const* d_in, const int* in_sizes, int n_in,
                              void* d_out, int out_size, void* d_ws, size_t ws_size,
                              hipStream_t stream) {
  const float* inp      = (const float*)d_in[0];
  const float* x_obs    = (const float*)d_in[1];
  const float* patterns = (const float*)d_in[2];
  const float* h0       = (const float*)d_in[3];
  const float* W_ih     = (const float*)d_in[4];
  const float* W_hh     = (const float*)d_in[5];
  const float* b_ih     = (const float*)d_in[6];
  const float* b_hh     = (const float*)d_in[7];

  float* out    = (float*)d_out;
  float* prob_g = out;                         // 1024*512
  float* prob_x = out + 524288;                // 1024*512
  float* g_cur  = out + 1048576;               // 1024*512
  float* h_last = out + 1572864;               // 512
  (void)prob_g; (void)prob_x;

  char* wsb = (char*)d_ws;
  unsigned* flags = (unsigned*)wsb;                            // 4 KB
  float* xw  = (float*)(wsb + 4096);                           // 2 MB
  float* bkx = (float*)(wsb + 4096 + 2097152);                 // 128 KB
  float* bkg = bkx + M_PAT;                                    // 128 KB
  size_t fixed = 4096 + 2097152 + 2 * (size_t)M_PAT * 4;

  int S = 8;
  while (S > 1) {
    size_t need = fixed + (size_t)S * 16384 + (size_t)S * 4194304;
    if (need <= ws_size) break;
    S >>= 1;
  }
  float* pml  = (float*)(wsb + fixed);
  float* pacc = pml + (size_t)2 * S * T_STEPS * 2;

  hipMemsetAsync(flags, 0, 4096, stream);
  xw_kernel<<<T_STEPS, 256, 0, stream>>>(inp, W_ih, b_ih, b_hh, xw);
  scan_kernel<<<SCAN_WGS, 256, 0, stream>>>(W_hh, xw, h0, g_cur, h_last, flags);
  norms_kernel<<<M_PAT / 4, 256, 0, stream>>>(patterns, bkx, bkg);
  flash_kernel<<<2 * 32 * S, 256, 0, stream>>>(g_cur, x_obs, patterns, bkx, bkg,
                                               pacc, pml, S);
  combine_kernel<<<2 * T_STEPS, 256, 0, stream>>>(pacc, pml, out, S);
}

// Round 2
// 4693.737 us; speedup vs baseline: 2.7082x; 2.7082x over previous
//
#include <hip/hip_runtime.h>
#include <math.h>

#define T_STEPS 1024
#define I_DIM   128
#define H_DIM   512
#define O_DIM   512
#define M_PAT   32768
#define SCAN_WGS 8
#define VT_STR  32800   // padded key-stride of transposed V (breaks 64KB row aliasing)

typedef __attribute__((ext_vector_type(8))) short s16x8;
typedef __attribute__((ext_vector_type(4))) float f32x4;

__device__ __forceinline__ void bf_split(float f, unsigned short& hi, unsigned short& lo) {
  unsigned u = __builtin_bit_cast(unsigned, f);
  hi = (unsigned short)(u >> 16);                       // truncation split
  float r = f - __builtin_bit_cast(float, u & 0xFFFF0000u);
  lo = (unsigned short)(__builtin_bit_cast(unsigned, r) >> 16);
}
__device__ __forceinline__ unsigned short f2bf(float f) {
  return (unsigned short)(__builtin_bit_cast(unsigned, f) >> 16);
}
__device__ __forceinline__ float bf2f(unsigned short b) {
  return __builtin_bit_cast(float, ((unsigned)b) << 16);
}

// ---------------------------------------------------------------------------
// K0: xw[t][j] = inp[t,:] . W_ih[j,:] + b_ih[j] + b_hh[j]
// ---------------------------------------------------------------------------
__global__ __launch_bounds__(256) void xw_kernel(const float* __restrict__ inp,
    const float* __restrict__ W_ih, const float* __restrict__ b_ih,
    const float* __restrict__ b_hh, float* __restrict__ xw) {
  int t = blockIdx.x;
  __shared__ float4 xs4[I_DIM / 4];
  if (threadIdx.x < I_DIM / 4)
    xs4[threadIdx.x] = ((const float4*)(inp + (size_t)t * I_DIM))[threadIdx.x];
  __syncthreads();
  for (int j = threadIdx.x; j < H_DIM; j += 256) {
    const float4* w4 = (const float4*)(W_ih + (size_t)j * I_DIM);
    float acc = 0.f;
#pragma unroll
    for (int i = 0; i < I_DIM / 4; i++) {
      float4 w = w4[i]; float4 x = xs4[i];
      acc += w.x * x.x + w.y * x.y + w.z * x.z + w.w * x.w;
    }
    xw[(size_t)t * H_DIM + j] = acc + b_ih[j] + b_hh[j];
  }
}

// ---------------------------------------------------------------------------
// K1: RNN scan with XCD-affinity election. 128 WGs launched; 8 WGs on one XCD
// elected (flag/h traffic stays in that XCD's L2), rest exit. Deadlock-free:
// WG0 always decides once >=8 WGs registered in some (clamped) xcd bucket.
// ---------------------------------------------------------------------------
__global__ __launch_bounds__(256, 1) void scan_kernel(
    const float* __restrict__ W_hh, const float* __restrict__ xw,
    const float* __restrict__ h0, float* __restrict__ g_cur,
    float* __restrict__ h_last, unsigned* __restrict__ sync) {
  unsigned* flags = sync;          // [1024] per-step counters
  unsigned* cnt   = sync + 1024;   // [8] per-xcd registration
  unsigned* dec   = sync + 1032;   // decision word (0 = undecided)
  __shared__ int role_s;
  if (threadIdx.x == 0) {
    unsigned xcd = __builtin_amdgcn_s_getreg(6164) & 7u;  // HW_REG_XCC_ID (id 20, width 4)
    unsigned my_idx = __hip_atomic_fetch_add(&cnt[xcd], 1u, __ATOMIC_ACQ_REL,
                                             __HIP_MEMORY_SCOPE_AGENT);
    if (blockIdx.x == 0) {
      int chosen = -1;
      while (chosen < 0) {
        for (int x = 0; x < 8; x++)
          if (__hip_atomic_load(&cnt[x], __ATOMIC_ACQUIRE,
                                __HIP_MEMORY_SCOPE_AGENT) >= 8u) { chosen = x; break; }
        if (chosen < 0) __builtin_amdgcn_s_sleep(2);
      }
      __hip_atomic_store(dec, 1u + (unsigned)chosen, __ATOMIC_RELEASE,
                         __HIP_MEMORY_SCOPE_AGENT);
    }
    unsigned d;
    while ((d = __hip_atomic_load(dec, __ATOMIC_ACQUIRE,
                                  __HIP_MEMORY_SCOPE_AGENT)) == 0u)
      __builtin_amdgcn_s_sleep(2);
    role_s = (xcd == d - 1u && my_idx < 8u) ? (int)my_idx : -1;
  }
  __syncthreads();
  const int role = role_s;
  if (role < 0) return;

  const int lane = threadIdx.x & 63;
  const int part = threadIdx.x >> 6;
  const int row  = role * 64 + lane;

  float4 w[32];
  const float4* wsrc = (const float4*)(W_hh + (size_t)row * H_DIM + part * 128);
#pragma unroll
  for (int i = 0; i < 32; i++) w[i] = wsrc[i];

  __shared__ float4 h_s[H_DIM / 4];
  __shared__ float  red[4][64];

  for (int t = 0; t < T_STEPS; t++) {
    if (threadIdx.x == 0 && t > 0) {
      while (__hip_atomic_load(flags + (t - 1), __ATOMIC_ACQUIRE,
                               __HIP_MEMORY_SCOPE_AGENT) < SCAN_WGS) {
        __builtin_amdgcn_s_sleep(1);
      }
    }
    __syncthreads();
    const float4* hsrc = (t == 0) ? (const float4*)h0
                                  : (const float4*)(g_cur + (size_t)(t - 1) * H_DIM);
    if (threadIdx.x < H_DIM / 4) h_s[threadIdx.x] = hsrc[threadIdx.x];
    __syncthreads();

    float acc = 0.f;
#pragma unroll
    for (int i = 0; i < 32; i++) {
      float4 h4 = h_s[part * 32 + i];
      acc += h4.x * w[i].x + h4.y * w[i].y + h4.z * w[i].z + h4.w * w[i].w;
    }
    red[part][lane] = acc;
    __syncthreads();

    if (part == 0) {
      float pre = red[0][lane] + red[1][lane] + red[2][lane] + red[3][lane]
                + xw[(size_t)t * H_DIM + row];
      // fast tanh: 1 - 2/(e^{2x}+1)
      float e = __expf(2.f * pre);
      float h = 1.f - 2.f / (e + 1.f);
      g_cur[(size_t)t * H_DIM + row] = h;
      if (t == T_STEPS - 1) h_last[row] = h;
      __threadfence();
      if (lane == 0)
        __hip_atomic_fetch_add(flags + t, 1u, __ATOMIC_RELEASE,
                               __HIP_MEMORY_SCOPE_AGENT);
    }
  }
}

// ---------------------------------------------------------------------------
// K2: key norms. bkx[m] = 8*||x_vals[m]||^2, bkg[m] = 8*||g_keys[m]||^2
// ---------------------------------------------------------------------------
__global__ __launch_bounds__(256) void norms_kernel(const float* __restrict__ patterns,
    float* __restrict__ bkx, float* __restrict__ bkg) {
  int lane = threadIdx.x & 63;
  int m = blockIdx.x * 4 + (threadIdx.x >> 6);
  const float4* row = (const float4*)(patterns + (size_t)m * (O_DIM + H_DIM));
  float ax = 0.f, ag = 0.f;
#pragma unroll
  for (int jj = 0; jj < 4; jj++) {
    float4 v = row[lane + 64 * jj];
    float s = v.x * v.x + v.y * v.y + v.z * v.z + v.w * v.w;
    if (jj < 2) ax += s; else ag += s;
  }
#pragma unroll
  for (int off = 1; off < 64; off <<= 1) {
    ax += __shfl_xor(ax, off, 64);
    ag += __shfl_xor(ag, off, 64);
  }
  if (lane == 0) { bkx[m] = 8.f * ax; bkg[m] = 8.f * ag; }
}

// ---------------------------------------------------------------------------
// K3: transpose x_vals -> Vt[vd][key] bf16 (trunc), padded stride VT_STR.
// ---------------------------------------------------------------------------
__global__ __launch_bounds__(256) void vt_kernel(const float* __restrict__ patterns,
                                                 unsigned short* __restrict__ Vt) {
  __shared__ unsigned short tile[64 * 68];
  int kt = blockIdx.x;   // key tile (64 keys)
  int vt = blockIdx.y;   // vd tile  (64 dims)
#pragma unroll
  for (int i = 0; i < 4; i++) {
    int f = threadIdx.x + 256 * i;        // 0..1023 : 64 keys x 16 float4
    int key = f >> 4, c4 = f & 15;
    float4 v = *(const float4*)(patterns + (size_t)(kt * 64 + key) * 1024 + vt * 64 + c4 * 4);
    unsigned short* dst = &tile[key * 68 + c4 * 4];
    dst[0] = f2bf(v.x); dst[1] = f2bf(v.y); dst[2] = f2bf(v.z); dst[3] = f2bf(v.w);
  }
  __syncthreads();
  int vd = threadIdx.x >> 2, q4 = threadIdx.x & 3;
  unsigned short tmp[16];
#pragma unroll
  for (int k = 0; k < 16; k++) tmp[k] = tile[(q4 * 16 + k) * 68 + vd];
  size_t ob = (size_t)(vt * 64 + vd) * VT_STR + kt * 64 + q4 * 16;
#pragma unroll
  for (int h = 0; h < 2; h++) {
    s16x8 pk;
#pragma unroll
    for (int j = 0; j < 8; j++) pk[j] = (short)tmp[h * 8 + j];
    *(s16x8*)&Vt[ob + h * 8] = pk;
  }
}

// ---------------------------------------------------------------------------
// K4: MFMA flash retrieval. logits = 16*(q.k) - 8*||k||^2, online softmax,
// split-bf16 QK (hi*hi + hi*lo + lo*hi), bf16 P & V for PV.
// Block: 512 thr (8 waves). Q-tile 32 (2 groups of 16). Key tile 64.
// Wave (qg,kw): scores for its 16 queries x keys [kw*16,+16); PV for vd slice
// [kw*128,+128). K staged to LDS hi/lo bf16 XOR-swizzled. Skip-PV when tile
// max logit < running max - 25.
// ---------------------------------------------------------------------------
template <bool USE_VT>
__global__ __launch_bounds__(512, 2) void flash_kernel(
    const float* __restrict__ Qg, const float* __restrict__ Qx,
    const float* __restrict__ patterns, const float* __restrict__ bkx,
    const float* __restrict__ bkg, const unsigned short* __restrict__ Vt,
    float* __restrict__ pacc, float* __restrict__ pml, int S) {
  const int bid  = blockIdx.x;
  const int sidx = bid >> 6;            // key-split slow for L2 grouping
  const int ret  = (bid >> 5) & 1;
  const int qt   = bid & 31;
  const int qbase = qt * 32;

  const float* Qp  = ret ? Qx : Qg;
  const float* Kp  = patterns + (ret ? 0 : O_DIM);   // key cols
  const float* bkk = ret ? bkx : bkg;

  const int chunk = M_PAT / S;
  const int kbeg = sidx * chunk, kend = kbeg + chunk;

  const int lane = threadIdx.x & 63;
  const int wid  = threadIdx.x >> 6;    // 0..7
  const int qg   = wid >> 2;            // query group
  const int kw   = wid & 3;             // key sub-block / vd slice
  const int quad = lane >> 4;
  const int l16  = lane & 15;

  __shared__ unsigned short stage_u16[16384];       // 32 KB: khi[0..8191], klo[8192..]; aliases S_f
  __shared__ unsigned short p_lds[32 * 72];         // P bf16, padded stride 72
  __shared__ float mrow_s[32], lrow_s[32], alpha_s[32];
  __shared__ int flag_s;

  // ---- load Q fragments (A-layout: m=l16, k=quad*8+j), split hi/lo ----
  const int qrow = qbase + qg * 16 + l16;
  s16x8 qhi[16], qlo[16];
#pragma unroll
  for (int kst = 0; kst < 16; kst++) {
    const float4* src = (const float4*)(Qp + (size_t)qrow * 512 + kst * 32 + quad * 8);
    float4 a = src[0], b = src[1];
    float fv[8] = {a.x, a.y, a.z, a.w, b.x, b.y, b.z, b.w};
    s16x8 h, l;
#pragma unroll
    for (int j = 0; j < 8; j++) {
      unsigned short hb, lb; bf_split(fv[j], hb, lb);
      h[j] = (short)hb; l[j] = (short)lb;
    }
    qhi[kst] = h; qlo[kst] = l;
  }

  if (threadIdx.x < 32) { mrow_s[threadIdx.x] = -INFINITY; lrow_s[threadIdx.x] = 0.f; }

  f32x4 o[8];
#pragma unroll
  for (int nb = 0; nb < 8; nb++) o[nb] = (f32x4){0.f, 0.f, 0.f, 0.f};
  float ov[32];
  if (!USE_VT) {
#pragma unroll
    for (int j = 0; j < 32; j++) ov[j] = 0.f;
  }
  const int row2 = threadIdx.x >> 4;   // 0..31 (phase-2 / VALU-PV row)
  const int c0   = threadIdx.x & 15;

  for (int k0 = kbeg; k0 < kend; k0 += 64) {
    // ---------------- phase 1: scores ----------------
    f32x4 sc = (f32x4){0.f, 0.f, 0.f, 0.f};
#pragma unroll
    for (int dc = 0; dc < 4; dc++) {
      __syncthreads();                       // stage buffer free (prev reads done)
      if (dc == 0 && threadIdx.x == 0) flag_s = 0;
#pragma unroll
      for (int i = 0; i < 2; i++) {
        int oid = threadIdx.x + 512 * i;     // 1024 octets: key*16 + oct
        int key = oid >> 4, oct = oid & 15;
        const float4* src = (const float4*)(Kp + (size_t)(k0 + key) * 1024 + dc * 128 + oct * 8);
        float4 a = src[0], b = src[1];
        float fv[8] = {a.x, a.y, a.z, a.w, b.x, b.y, b.z, b.w};
        s16x8 hv, lv;
#pragma unroll
        for (int j = 0; j < 8; j++) {
          unsigned short hb, lb; bf_split(fv[j], hb, lb);
          hv[j] = (short)hb; lv[j] = (short)lb;
        }
        int base = (key * 16 + (oct ^ (key & 7))) * 8;
        *(s16x8*)&stage_u16[base] = hv;
        *(s16x8*)&stage_u16[8192 + base] = lv;
      }
      __syncthreads();
#pragma unroll
      for (int ks = 0; ks < 4; ks++) {
        int kst = dc * 4 + ks;
        int key = kw * 16 + l16;
        int oct = ks * 4 + quad;
        int base = (key * 16 + (oct ^ (key & 7))) * 8;
        s16x8 kh = *(const s16x8*)&stage_u16[base];
        s16x8 kl = *(const s16x8*)&stage_u16[8192 + base];
        sc = __builtin_amdgcn_mfma_f32_16x16x32_bf16(qhi[kst], kh, sc, 0, 0, 0);
        sc = __builtin_amdgcn_mfma_f32_16x16x32_bf16(qlo[kst], kh, sc, 0, 0, 0);
        sc = __builtin_amdgcn_mfma_f32_16x16x32_bf16(qhi[kst], kl, sc, 0, 0, 0);
      }
    }
    float bkv = bkk[k0 + kw * 16 + l16];
    __syncthreads();                         // all K reads done; stage aliases S_f now
    float* S_f = (float*)stage_u16;          // [32][68]
#pragma unroll
    for (int r = 0; r < 4; r++)
      S_f[(qg * 16 + quad * 4 + r) * 68 + kw * 16 + l16] = 16.f * sc[r] - bkv;
    __syncthreads();

    // ---------------- phase 2: online softmax ----------------
    float s4[4], p4[4];
#pragma unroll
    for (int c = 0; c < 4; c++) s4[c] = S_f[row2 * 68 + c0 + 16 * c];
    float tmax = fmaxf(fmaxf(s4[0], s4[1]), fmaxf(s4[2], s4[3]));
#pragma unroll
    for (int off = 1; off < 16; off <<= 1) tmax = fmaxf(tmax, __shfl_xor(tmax, off, 16));
    float mold = mrow_s[row2];
    float mnew = fmaxf(mold, tmax);
    float tsum = 0.f;
#pragma unroll
    for (int c = 0; c < 4; c++) { p4[c] = __expf(s4[c] - mnew); tsum += p4[c]; }
#pragma unroll
    for (int off = 1; off < 16; off <<= 1) tsum += __shfl_xor(tsum, off, 16);
#pragma unroll
    for (int c = 0; c < 4; c++) p_lds[row2 * 72 + c0 + 16 * c] = f2bf(p4[c]);
    if (c0 == 0) {
      float al = __expf(mold - mnew);
      alpha_s[row2] = al;
      mrow_s[row2] = mnew;
      lrow_s[row2] = lrow_s[row2] * al + tsum;
      if (tmax > mold - 25.f) flag_s = 1;
    }
    __syncthreads();
    const int doPV = flag_s;

    // ---------------- phase 3: PV ----------------
    if (doPV) {
      if (USE_VT) {
        float alr[4];
#pragma unroll
        for (int r = 0; r < 4; r++) alr[r] = alpha_s[qg * 16 + quad * 4 + r];
#pragma unroll
        for (int nb = 0; nb < 8; nb++) {
          o[nb][0] *= alr[0]; o[nb][1] *= alr[1]; o[nb][2] *= alr[2]; o[nb][3] *= alr[3];
        }
#pragma unroll
        for (int ks2 = 0; ks2 < 2; ks2++) {
          s16x8 pf = *(const s16x8*)&p_lds[(qg * 16 + l16) * 72 + ks2 * 32 + quad * 8];
#pragma unroll
          for (int nb = 0; nb < 8; nb++) {
            int vd = kw * 128 + nb * 16 + l16;
            s16x8 vf = *(const s16x8*)(Vt + (size_t)vd * VT_STR + (k0 + ks2 * 32 + quad * 8));
            o[nb] = __builtin_amdgcn_mfma_f32_16x16x32_bf16(pf, vf, o[nb], 0, 0, 0);
          }
        }
      } else {
        float al = alpha_s[row2];
#pragma unroll
        for (int j = 0; j < 32; j++) ov[j] *= al;
        for (int key = 0; key < 64; key++) {
          float w = bf2f(p_lds[row2 * 72 + key]);
          const float4* vsrc = (const float4*)(patterns + (size_t)(k0 + key) * 1024 + c0 * 32);
#pragma unroll
          for (int j = 0; j < 8; j++) {
            float4 v = vsrc[j];
            ov[4 * j + 0] += w * v.x; ov[4 * j + 1] += w * v.y;
            ov[4 * j + 2] += w * v.z; ov[4 * j + 3] += w * v.w;
          }
        }
      }
    }
  }

  // ---------------- epilogue: unnormalized partials + (m,l) ----------------
  __syncthreads();
  size_t pbase = ((size_t)(ret * S + sidx) * T_STEPS + qbase);
  if (USE_VT) {
#pragma unroll
    for (int nb = 0; nb < 8; nb++)
#pragma unroll
      for (int r = 0; r < 4; r++)
        pacc[(pbase + qg * 16 + quad * 4 + r) * 512 + kw * 128 + nb * 16 + l16] = o[nb][r];
  } else {
#pragma unroll
    for (int j = 0; j < 32; j++)
      pacc[(pbase + row2) * 512 + c0 * 32 + j] = ov[j];
  }
  if (threadIdx.x < 32) {
    pml[(pbase + threadIdx.x) * 2]     = mrow_s[threadIdx.x];
    pml[(pbase + threadIdx.x) * 2 + 1] = lrow_s[threadIdx.x];
  }
}

// ---------------------------------------------------------------------------
// K5: combine key-split partials -> prob_g / prob_x
// ---------------------------------------------------------------------------
__global__ __launch_bounds__(256) void combine_kernel(
    const float* __restrict__ pacc, const float* __restrict__ pml,
    float* __restrict__ out, int S) {
  int b = blockIdx.x;              // ret*1024 + r
  int ret = b >> 10, r = b & 1023;
  float M = -INFINITY;
  for (int s = 0; s < S; s++)
    M = fmaxf(M, pml[((size_t)(ret * S + s) * T_STEPS + r) * 2]);
  float L = 0.f;
  for (int s = 0; s < S; s++) {
    size_t mb = ((size_t)(ret * S + s) * T_STEPS + r) * 2;
    L += pml[mb + 1] * __expf(pml[mb] - M);
  }
  float inv = 1.0f / L;
  for (int cc = threadIdx.x; cc < 512; cc += 256) {
    float acc = 0.f;
    for (int s = 0; s < S; s++) {
      size_t mb = ((size_t)(ret * S + s) * T_STEPS + r) * 2;
      float sc = __expf(pml[mb] - M);
      acc += sc * pacc[((size_t)(ret * S + s) * T_STEPS + r) * 512 + cc];
    }
    out[(size_t)ret * (T_STEPS * O_DIM) + (size_t)r * 512 + cc] = acc * inv;
  }
}

// ---------------------------------------------------------------------------
extern "C" void kernel_launch(void* const* d_in, const int* in_sizes, int n_in,
                              void* d_out, int out_size, void* d_ws, size_t ws_size,
                              hipStream_t stream) {
  const float* inp      = (const float*)d_in[0];
  const float* x_obs    = (const float*)d_in[1];
  const float* patterns = (const float*)d_in[2];
  const float* h0       = (const float*)d_in[3];
  const float* W_ih     = (const float*)d_in[4];
  const float* W_hh     = (const float*)d_in[5];
  const float* b_ih     = (const float*)d_in[6];
  const float* b_hh     = (const float*)d_in[7];

  float* out    = (float*)d_out;
  float* g_cur  = out + 1048576;               // 1024*512
  float* h_last = out + 1572864;               // 512

  char* wsb = (char*)d_ws;
  size_t off = 0;
  auto alloc = [&](size_t bytes) -> char* {
    char* p = wsb + off; off += (bytes + 255) & ~(size_t)255; return p;
  };
  unsigned* sync = (unsigned*)alloc(8192);
  float* xw  = (float*)alloc((size_t)T_STEPS * H_DIM * 4);
  float* bkx = (float*)alloc((size_t)M_PAT * 4);
  float* bkg = (float*)alloc((size_t)M_PAT * 4);
  size_t base = off;

  const size_t vt_bytes = (size_t)512 * VT_STR * 2;
  auto pml_bytes  = [](int S) { return (size_t)2 * S * T_STEPS * 2 * 4; };
  auto pacc_bytes = [](int S) { return (size_t)2 * S * T_STEPS * 512 * 4; };

  int S = 4; bool use_vt = false;
  if (base + pml_bytes(4) + pacc_bytes(4) + vt_bytes + 1024 <= ws_size) { S = 4; use_vt = true; }
  else if (base + pml_bytes(2) + pacc_bytes(2) + vt_bytes + 1024 <= ws_size) { S = 2; use_vt = true; }
  else if (base + pml_bytes(4) + pacc_bytes(4) + 1024 <= ws_size) { S = 4; use_vt = false; }
  else if (base + pml_bytes(2) + pacc_bytes(2) + 1024 <= ws_size) { S = 2; use_vt = false; }
  else { S = 1; use_vt = false; }

  float* pml  = (float*)alloc(pml_bytes(S));
  float* pacc = (float*)alloc(pacc_bytes(S));
  unsigned short* Vt = use_vt ? (unsigned short*)alloc(vt_bytes) : (unsigned short*)nullptr;

  hipMemsetAsync(sync, 0, 8192, stream);
  xw_kernel<<<T_STEPS, 256, 0, stream>>>(inp, W_ih, b_ih, b_hh, xw);
  scan_kernel<<<128, 256, 0, stream>>>(W_hh, xw, h0, g_cur, h_last, sync);
  norms_kernel<<<M_PAT / 4, 256, 0, stream>>>(patterns, bkx, bkg);
  if (use_vt) {
    vt_kernel<<<dim3(512, 8), 256, 0, stream>>>(patterns, Vt);
    flash_kernel<true><<<S * 64, 512, 0, stream>>>(g_cur, x_obs, patterns, bkx, bkg,
                                                   Vt, pacc, pml, S);
  } else {
    flash_kernel<false><<<S * 64, 512, 0, stream>>>(g_cur, x_obs, patterns, bkx, bkg,
                                                    nullptr, pacc, pml, S);
  }
  combine_kernel<<<2 * T_STEPS, 256, 0, stream>>>(pacc, pml, out, S);
}

// Round 4
// 3222.906 us; speedup vs baseline: 3.9441x; 1.4564x over previous
//
#include <hip/hip_runtime.h>
#include <math.h>

#define T_STEPS 1024
#define I_DIM   128
#define H_DIM   512
#define O_DIM   512
#define M_PAT   32768
#define SCAN_WGS 8
#define VT_STR  32800   // padded key-stride of transposed V (breaks 64KB row aliasing)

typedef __attribute__((ext_vector_type(8))) short s16x8;
typedef __attribute__((ext_vector_type(4))) float f32x4;

__device__ __forceinline__ void bf_split(float f, unsigned short& hi, unsigned short& lo) {
  unsigned u = __builtin_bit_cast(unsigned, f);
  hi = (unsigned short)(u >> 16);                       // truncation split
  float r = f - __builtin_bit_cast(float, u & 0xFFFF0000u);
  lo = (unsigned short)(__builtin_bit_cast(unsigned, r) >> 16);
}
__device__ __forceinline__ unsigned short f2bf(float f) {
  return (unsigned short)(__builtin_bit_cast(unsigned, f) >> 16);
}
__device__ __forceinline__ float bf2f(unsigned short b) {
  return __builtin_bit_cast(float, ((unsigned)b) << 16);
}

// ---------------------------------------------------------------------------
// K0: xw[t][j] = inp[t,:] . W_ih[j,:] + b_ih[j] + b_hh[j]
// ---------------------------------------------------------------------------
__global__ __launch_bounds__(256) void xw_kernel(const float* __restrict__ inp,
    const float* __restrict__ W_ih, const float* __restrict__ b_ih,
    const float* __restrict__ b_hh, float* __restrict__ xw) {
  int t = blockIdx.x;
  __shared__ float4 xs4[I_DIM / 4];
  if (threadIdx.x < I_DIM / 4)
    xs4[threadIdx.x] = ((const float4*)(inp + (size_t)t * I_DIM))[threadIdx.x];
  __syncthreads();
  for (int j = threadIdx.x; j < H_DIM; j += 256) {
    const float4* w4 = (const float4*)(W_ih + (size_t)j * I_DIM);
    float acc = 0.f;
#pragma unroll
    for (int i = 0; i < I_DIM / 4; i++) {
      float4 w = w4[i]; float4 x = xs4[i];
      acc += w.x * x.x + w.y * x.y + w.z * x.z + w.w * x.w;
    }
    xw[(size_t)t * H_DIM + j] = acc + b_ih[j] + b_hh[j];
  }
}

// ---------------------------------------------------------------------------
// K1: RNN scan. 128 WGs launched; 8 WGs on ONE XCD elected, rest exit.
// ALL cross-WG traffic is relaxed agent-scope atomics (compile to L1-bypassing
// loads/stores at the coherence point, NO buffer_inv anywhere in the loop).
// Producer: relaxed-atomic h stores, then RELEASE tag store (waitcnt+store).
// Consumer: relaxed-atomic tag poll, then relaxed-atomic h loads -> LDS.
// Correct at agent scope regardless of XCD placement; election makes it fast.
// ---------------------------------------------------------------------------
__global__ __launch_bounds__(256, 1) void scan_kernel(
    const float* __restrict__ W_hh, const float* __restrict__ xw,
    const float* __restrict__ h0, float* __restrict__ g_cur,
    float* __restrict__ h_last, unsigned* __restrict__ sync) {
  unsigned* tags = sync;           // [8] per-WG step tags (monotonic t+1)
  unsigned* cnt  = sync + 64;      // [8] per-xcd registration
  unsigned* dec  = sync + 128;     // decision word (0 = undecided)
  __shared__ int role_s;
  if (threadIdx.x == 0) {
    unsigned xcd = __builtin_amdgcn_s_getreg(6164) & 7u;  // HW_REG_XCC_ID
    unsigned my_idx = __hip_atomic_fetch_add(&cnt[xcd], 1u, __ATOMIC_ACQ_REL,
                                             __HIP_MEMORY_SCOPE_AGENT);
    if (blockIdx.x == 0) {
      int chosen = -1;
      while (chosen < 0) {
        for (int x = 0; x < 8; x++)
          if (__hip_atomic_load(&cnt[x], __ATOMIC_ACQUIRE,
                                __HIP_MEMORY_SCOPE_AGENT) >= 8u) { chosen = x; break; }
        if (chosen < 0) __builtin_amdgcn_s_sleep(2);
      }
      __hip_atomic_store(dec, 1u + (unsigned)chosen, __ATOMIC_RELEASE,
                         __HIP_MEMORY_SCOPE_AGENT);
    }
    unsigned d;
    while ((d = __hip_atomic_load(dec, __ATOMIC_ACQUIRE,
                                  __HIP_MEMORY_SCOPE_AGENT)) == 0u)
      __builtin_amdgcn_s_sleep(2);
    role_s = (xcd == d - 1u && my_idx < 8u) ? (int)my_idx : -1;
  }
  __syncthreads();
  const int role = role_s;
  if (role < 0) return;

  const int lane = threadIdx.x & 63;
  const int part = threadIdx.x >> 6;     // k-chunk 0..3 (128 cols each)
  const int row  = role * 64 + lane;

  float4 w[32];
  const float4* wsrc = (const float4*)(W_hh + (size_t)row * H_DIM + part * 128);
#pragma unroll
  for (int i = 0; i < 32; i++) w[i] = wsrc[i];

  __shared__ float h_sf[H_DIM];
  __shared__ float red[4][64];

  float xw_next = xw[row];               // xw[0*H + row]

  for (int t = 0; t < T_STEPS; t++) {
    float xwv = xw_next;
    if (part == 0 && t + 1 < T_STEPS)
      xw_next = xw[(size_t)(t + 1) * H_DIM + row];   // prefetch, hides HBM lat

    if (part == 0 && t > 0) {
      const unsigned* tp = tags + (lane & 7);
      unsigned tv;
      do {
        tv = __hip_atomic_load(tp, __ATOMIC_RELAXED, __HIP_MEMORY_SCOPE_AGENT);
      } while (__ballot(tv < (unsigned)t) != 0ull);
    }
    __syncthreads();

    // stage h into LDS via L1-bypassing relaxed agent atomic loads
    const unsigned* hsrc = (const unsigned*)((t == 0) ? h0
                                 : g_cur + (size_t)(t - 1) * H_DIM);
    unsigned v0 = __hip_atomic_load(hsrc + threadIdx.x, __ATOMIC_RELAXED,
                                    __HIP_MEMORY_SCOPE_AGENT);
    unsigned v1 = __hip_atomic_load(hsrc + 256 + threadIdx.x, __ATOMIC_RELAXED,
                                    __HIP_MEMORY_SCOPE_AGENT);
    h_sf[threadIdx.x]       = __builtin_bit_cast(float, v0);
    h_sf[256 + threadIdx.x] = __builtin_bit_cast(float, v1);
    __syncthreads();

    const float4* h4 = (const float4*)h_sf + part * 32;
    float a0 = 0.f, a1 = 0.f, a2 = 0.f, a3 = 0.f;
#pragma unroll
    for (int i = 0; i < 8; i++) {
      float4 x0 = h4[4 * i], x1 = h4[4 * i + 1], x2 = h4[4 * i + 2], x3 = h4[4 * i + 3];
      float4 w0 = w[4 * i], w1 = w[4 * i + 1], w2 = w[4 * i + 2], w3 = w[4 * i + 3];
      a0 += x0.x * w0.x + x0.y * w0.y + x0.z * w0.z + x0.w * w0.w;
      a1 += x1.x * w1.x + x1.y * w1.y + x1.z * w1.z + x1.w * w1.w;
      a2 += x2.x * w2.x + x2.y * w2.y + x2.z * w2.z + x2.w * w2.w;
      a3 += x3.x * w3.x + x3.y * w3.y + x3.z * w3.z + x3.w * w3.w;
    }
    red[part][lane] = (a0 + a1) + (a2 + a3);
    __syncthreads();

    if (part == 0) {
      float pre = red[0][lane] + red[1][lane] + red[2][lane] + red[3][lane] + xwv;
      float e = __expf(2.f * pre);
      float h = 1.f - 2.f / (e + 1.f);
      __hip_atomic_store((unsigned*)(g_cur + (size_t)t * H_DIM + row),
                         __builtin_bit_cast(unsigned, h),
                         __ATOMIC_RELAXED, __HIP_MEMORY_SCOPE_AGENT);
      if (t == T_STEPS - 1) h_last[row] = h;
      if (lane == 0)
        __hip_atomic_store(tags + role, (unsigned)(t + 1),
                           __ATOMIC_RELEASE, __HIP_MEMORY_SCOPE_AGENT);
    }
  }
}

// ---------------------------------------------------------------------------
// K2: key norms. bkx[m] = 8*||x_vals[m]||^2, bkg[m] = 8*||g_keys[m]||^2
// ---------------------------------------------------------------------------
__global__ __launch_bounds__(256) void norms_kernel(const float* __restrict__ patterns,
    float* __restrict__ bkx, float* __restrict__ bkg) {
  int lane = threadIdx.x & 63;
  int m = blockIdx.x * 4 + (threadIdx.x >> 6);
  const float4* row = (const float4*)(patterns + (size_t)m * (O_DIM + H_DIM));
  float ax = 0.f, ag = 0.f;
#pragma unroll
  for (int jj = 0; jj < 4; jj++) {
    float4 v = row[lane + 64 * jj];
    float s = v.x * v.x + v.y * v.y + v.z * v.z + v.w * v.w;
    if (jj < 2) ax += s; else ag += s;
  }
#pragma unroll
  for (int off = 1; off < 64; off <<= 1) {
    ax += __shfl_xor(ax, off, 64);
    ag += __shfl_xor(ag, off, 64);
  }
  if (lane == 0) { bkx[m] = 8.f * ax; bkg[m] = 8.f * ag; }
}

// ---------------------------------------------------------------------------
// K3: transpose x_vals -> Vt[vd][key] bf16 (trunc), padded stride VT_STR.
// ---------------------------------------------------------------------------
__global__ __launch_bounds__(256) void vt_kernel(const float* __restrict__ patterns,
                                                 unsigned short* __restrict__ Vt) {
  __shared__ unsigned short tile[64 * 68];
  int kt = blockIdx.x;   // key tile (64 keys)
  int vt = blockIdx.y;   // vd tile  (64 dims)
#pragma unroll
  for (int i = 0; i < 4; i++) {
    int f = threadIdx.x + 256 * i;        // 0..1023 : 64 keys x 16 float4
    int key = f >> 4, c4 = f & 15;
    float4 v = *(const float4*)(patterns + (size_t)(kt * 64 + key) * 1024 + vt * 64 + c4 * 4);
    unsigned short* dst = &tile[key * 68 + c4 * 4];
    dst[0] = f2bf(v.x); dst[1] = f2bf(v.y); dst[2] = f2bf(v.z); dst[3] = f2bf(v.w);
  }
  __syncthreads();
  int vd = threadIdx.x >> 2, q4 = threadIdx.x & 3;
  unsigned short tmp[16];
#pragma unroll
  for (int k = 0; k < 16; k++) tmp[k] = tile[(q4 * 16 + k) * 68 + vd];
  size_t ob = (size_t)(vt * 64 + vd) * VT_STR + kt * 64 + q4 * 16;
#pragma unroll
  for (int h = 0; h < 2; h++) {
    s16x8 pk;
#pragma unroll
    for (int j = 0; j < 8; j++) pk[j] = (short)tmp[h * 8 + j];
    *(s16x8*)&Vt[ob + h * 8] = pk;
  }
}

// ---------------------------------------------------------------------------
// K4: MFMA flash retrieval. logits = 16*(q.k) - 8*||k||^2, online softmax,
// split-bf16 QK (hi*hi + hi*lo + lo*hi), bf16 P & V for PV.
// ---------------------------------------------------------------------------
template <bool USE_VT>
__global__ __launch_bounds__(512, 2) void flash_kernel(
    const float* __restrict__ Qg, const float* __restrict__ Qx,
    const float* __restrict__ patterns, const float* __restrict__ bkx,
    const float* __restrict__ bkg, const unsigned short* __restrict__ Vt,
    float* __restrict__ pacc, float* __restrict__ pml, int S) {
  const int bid  = blockIdx.x;
  const int sidx = bid >> 6;            // key-split slow for L2 grouping
  const int ret  = (bid >> 5) & 1;
  const int qt   = bid & 31;
  const int qbase = qt * 32;

  const float* Qp  = ret ? Qx : Qg;
  const float* Kp  = patterns + (ret ? 0 : O_DIM);   // key cols
  const float* bkk = ret ? bkx : bkg;

  const int chunk = M_PAT / S;
  const int kbeg = sidx * chunk, kend = kbeg + chunk;

  const int lane = threadIdx.x & 63;
  const int wid  = threadIdx.x >> 6;    // 0..7
  const int qg   = wid >> 2;            // query group
  const int kw   = wid & 3;             // key sub-block / vd slice
  const int quad = lane >> 4;
  const int l16  = lane & 15;

  __shared__ unsigned short stage_u16[16384];       // 32 KB: khi / klo; aliases S_f
  __shared__ unsigned short p_lds[32 * 72];         // P bf16, padded stride 72
  __shared__ float mrow_s[32], lrow_s[32], alpha_s[32];
  __shared__ int flag_s;

  // ---- load Q fragments (A-layout: m=l16, k=quad*8+j), split hi/lo ----
  const int qrow = qbase + qg * 16 + l16;
  s16x8 qhi[16], qlo[16];
#pragma unroll
  for (int kst = 0; kst < 16; kst++) {
    const float4* src = (const float4*)(Qp + (size_t)qrow * 512 + kst * 32 + quad * 8);
    float4 a = src[0], b = src[1];
    float fv[8] = {a.x, a.y, a.z, a.w, b.x, b.y, b.z, b.w};
    s16x8 h, l;
#pragma unroll
    for (int j = 0; j < 8; j++) {
      unsigned short hb, lb; bf_split(fv[j], hb, lb);
      h[j] = (short)hb; l[j] = (short)lb;
    }
    qhi[kst] = h; qlo[kst] = l;
  }

  if (threadIdx.x < 32) { mrow_s[threadIdx.x] = -INFINITY; lrow_s[threadIdx.x] = 0.f; }

  f32x4 o[8];
#pragma unroll
  for (int nb = 0; nb < 8; nb++) o[nb] = (f32x4){0.f, 0.f, 0.f, 0.f};
  float ov[32];
  if (!USE_VT) {
#pragma unroll
    for (int j = 0; j < 32; j++) ov[j] = 0.f;
  }
  const int row2 = threadIdx.x >> 4;   // 0..31 (phase-2 / VALU-PV row)
  const int c0   = threadIdx.x & 15;

  for (int k0 = kbeg; k0 < kend; k0 += 64) {
    // ---------------- phase 1: scores ----------------
    f32x4 sc = (f32x4){0.f, 0.f, 0.f, 0.f};
#pragma unroll
    for (int dc = 0; dc < 4; dc++) {
      __syncthreads();                       // stage buffer free (prev reads done)
      if (dc == 0 && threadIdx.x == 0) flag_s = 0;
#pragma unroll
      for (int i = 0; i < 2; i++) {
        int oid = threadIdx.x + 512 * i;     // 1024 octets: key*16 + oct
        int key = oid >> 4, oct = oid & 15;
        const float4* src = (const float4*)(Kp + (size_t)(k0 + key) * 1024 + dc * 128 + oct * 8);
        float4 a = src[0], b = src[1];
        float fv[8] = {a.x, a.y, a.z, a.w, b.x, b.y, b.z, b.w};
        s16x8 hv, lv;
#pragma unroll
        for (int j = 0; j < 8; j++) {
          unsigned short hb, lb; bf_split(fv[j], hb, lb);
          hv[j] = (short)hb; lv[j] = (short)lb;
        }
        int base = (key * 16 + (oct ^ (key & 7))) * 8;
        *(s16x8*)&stage_u16[base] = hv;
        *(s16x8*)&stage_u16[8192 + base] = lv;
      }
      __syncthreads();
#pragma unroll
      for (int ks = 0; ks < 4; ks++) {
        int kst = dc * 4 + ks;
        int key = kw * 16 + l16;
        int oct = ks * 4 + quad;
        int base = (key * 16 + (oct ^ (key & 7))) * 8;
        s16x8 kh = *(const s16x8*)&stage_u16[base];
        s16x8 kl = *(const s16x8*)&stage_u16[8192 + base];
        sc = __builtin_amdgcn_mfma_f32_16x16x32_bf16(qhi[kst], kh, sc, 0, 0, 0);
        sc = __builtin_amdgcn_mfma_f32_16x16x32_bf16(qlo[kst], kh, sc, 0, 0, 0);
        sc = __builtin_amdgcn_mfma_f32_16x16x32_bf16(qhi[kst], kl, sc, 0, 0, 0);
      }
    }
    float bkv = bkk[k0 + kw * 16 + l16];
    __syncthreads();                         // all K reads done; stage aliases S_f now
    float* S_f = (float*)stage_u16;          // [32][68]
#pragma unroll
    for (int r = 0; r < 4; r++)
      S_f[(qg * 16 + quad * 4 + r) * 68 + kw * 16 + l16] = 16.f * sc[r] - bkv;
    __syncthreads();

    // ---------------- phase 2: online softmax ----------------
    float s4[4], p4[4];
#pragma unroll
    for (int c = 0; c < 4; c++) s4[c] = S_f[row2 * 68 + c0 + 16 * c];
    float tmax = fmaxf(fmaxf(s4[0], s4[1]), fmaxf(s4[2], s4[3]));
#pragma unroll
    for (int off = 1; off < 16; off <<= 1) tmax = fmaxf(tmax, __shfl_xor(tmax, off, 16));
    float mold = mrow_s[row2];
    float mnew = fmaxf(mold, tmax);
    float tsum = 0.f;
#pragma unroll
    for (int c = 0; c < 4; c++) { p4[c] = __expf(s4[c] - mnew); tsum += p4[c]; }
#pragma unroll
    for (int off = 1; off < 16; off <<= 1) tsum += __shfl_xor(tsum, off, 16);
#pragma unroll
    for (int c = 0; c < 4; c++) p_lds[row2 * 72 + c0 + 16 * c] = f2bf(p4[c]);
    if (c0 == 0) {
      float al = __expf(mold - mnew);
      alpha_s[row2] = al;
      mrow_s[row2] = mnew;
      lrow_s[row2] = lrow_s[row2] * al + tsum;
      if (tmax > mold - 25.f) flag_s = 1;
    }
    __syncthreads();
    const int doPV = flag_s;

    // ---------------- phase 3: PV ----------------
    if (doPV) {
      if (USE_VT) {
        float alr[4];
#pragma unroll
        for (int r = 0; r < 4; r++) alr[r] = alpha_s[qg * 16 + quad * 4 + r];
#pragma unroll
        for (int nb = 0; nb < 8; nb++) {
          o[nb][0] *= alr[0]; o[nb][1] *= alr[1]; o[nb][2] *= alr[2]; o[nb][3] *= alr[3];
        }
#pragma unroll
        for (int ks2 = 0; ks2 < 2; ks2++) {
          s16x8 pf = *(const s16x8*)&p_lds[(qg * 16 + l16) * 72 + ks2 * 32 + quad * 8];
#pragma unroll
          for (int nb = 0; nb < 8; nb++) {
            int vd = kw * 128 + nb * 16 + l16;
            s16x8 vf = *(const s16x8*)(Vt + (size_t)vd * VT_STR + (k0 + ks2 * 32 + quad * 8));
            o[nb] = __builtin_amdgcn_mfma_f32_16x16x32_bf16(pf, vf, o[nb], 0, 0, 0);
          }
        }
      } else {
        float al = alpha_s[row2];
#pragma unroll
        for (int j = 0; j < 32; j++) ov[j] *= al;
        for (int key = 0; key < 64; key++) {
          float w = bf2f(p_lds[row2 * 72 + key]);
          const float4* vsrc = (const float4*)(patterns + (size_t)(k0 + key) * 1024 + c0 * 32);
#pragma unroll
          for (int j = 0; j < 8; j++) {
            float4 v = vsrc[j];
            ov[4 * j + 0] += w * v.x; ov[4 * j + 1] += w * v.y;
            ov[4 * j + 2] += w * v.z; ov[4 * j + 3] += w * v.w;
          }
        }
      }
    }
  }

  // ---------------- epilogue: unnormalized partials + (m,l) ----------------
  __syncthreads();
  size_t pbase = ((size_t)(ret * S + sidx) * T_STEPS + qbase);
  if (USE_VT) {
#pragma unroll
    for (int nb = 0; nb < 8; nb++)
#pragma unroll
      for (int r = 0; r < 4; r++)
        pacc[(pbase + qg * 16 + quad * 4 + r) * 512 + kw * 128 + nb * 16 + l16] = o[nb][r];
  } else {
#pragma unroll
    for (int j = 0; j < 32; j++)
      pacc[(pbase + row2) * 512 + c0 * 32 + j] = ov[j];
  }
  if (threadIdx.x < 32) {
    pml[(pbase + threadIdx.x) * 2]     = mrow_s[threadIdx.x];
    pml[(pbase + threadIdx.x) * 2 + 1] = lrow_s[threadIdx.x];
  }
}

// ---------------------------------------------------------------------------
// K5: combine key-split partials -> prob_g / prob_x
// ---------------------------------------------------------------------------
__global__ __launch_bounds__(256) void combine_kernel(
    const float* __restrict__ pacc, const float* __restrict__ pml,
    float* __restrict__ out, int S) {
  int b = blockIdx.x;              // ret*1024 + r
  int ret = b >> 10, r = b & 1023;
  float M = -INFINITY;
  for (int s = 0; s < S; s++)
    M = fmaxf(M, pml[((size_t)(ret * S + s) * T_STEPS + r) * 2]);
  float L = 0.f;
  for (int s = 0; s < S; s++) {
    size_t mb = ((size_t)(ret * S + s) * T_STEPS + r) * 2;
    L += pml[mb + 1] * __expf(pml[mb] - M);
  }
  float inv = 1.0f / L;
  for (int cc = threadIdx.x; cc < 512; cc += 256) {
    float acc = 0.f;
    for (int s = 0; s < S; s++) {
      size_t mb = ((size_t)(ret * S + s) * T_STEPS + r) * 2;
      float sc = __expf(pml[mb] - M);
      acc += sc * pacc[((size_t)(ret * S + s) * T_STEPS + r) * 512 + cc];
    }
    out[(size_t)ret * (T_STEPS * O_DIM) + (size_t)r * 512 + cc] = acc * inv;
  }
}

// ---------------------------------------------------------------------------
extern "C" void kernel_launch(void* const* d_in, const int* in_sizes, int n_in,
                              void* d_out, int out_size, void* d_ws, size_t ws_size,
                              hipStream_t stream) {
  const float* inp      = (const float*)d_in[0];
  const float* x_obs    = (const float*)d_in[1];
  const float* patterns = (const float*)d_in[2];
  const float* h0       = (const float*)d_in[3];
  const float* W_ih     = (const float*)d_in[4];
  const float* W_hh     = (const float*)d_in[5];
  const float* b_ih     = (const float*)d_in[6];
  const float* b_hh     = (const float*)d_in[7];

  float* out    = (float*)d_out;
  float* g_cur  = out + 1048576;               // 1024*512
  float* h_last = out + 1572864;               // 512

  char* wsb = (char*)d_ws;
  size_t off = 0;
  auto alloc = [&](size_t bytes) -> char* {
    char* p = wsb + off; off += (bytes + 255) & ~(size_t)255; return p;
  };
  unsigned* sync = (unsigned*)alloc(8192);
  float* xw  = (float*)alloc((size_t)T_STEPS * H_DIM * 4);
  float* bkx = (float*)alloc((size_t)M_PAT * 4);
  float* bkg = (float*)alloc((size_t)M_PAT * 4);
  size_t base = off;

  const size_t vt_bytes = (size_t)512 * VT_STR * 2;
  auto pml_bytes  = [](int S) { return (size_t)2 * S * T_STEPS * 2 * 4; };
  auto pacc_bytes = [](int S) { return (size_t)2 * S * T_STEPS * 512 * 4; };

  int S = 4; bool use_vt = false;
  if (base + pml_bytes(4) + pacc_bytes(4) + vt_bytes + 1024 <= ws_size) { S = 4; use_vt = true; }
  else if (base + pml_bytes(2) + pacc_bytes(2) + vt_bytes + 1024 <= ws_size) { S = 2; use_vt = true; }
  else if (base + pml_bytes(4) + pacc_bytes(4) + 1024 <= ws_size) { S = 4; use_vt = false; }
  else if (base + pml_bytes(2) + pacc_bytes(2) + 1024 <= ws_size) { S = 2; use_vt = false; }
  else { S = 1; use_vt = false; }

  float* pml  = (float*)alloc(pml_bytes(S));
  float* pacc = (float*)alloc(pacc_bytes(S));
  unsigned short* Vt = use_vt ? (unsigned short*)alloc(vt_bytes) : (unsigned short*)nullptr;

  hipMemsetAsync(sync, 0, 8192, stream);
  xw_kernel<<<T_STEPS, 256, 0, stream>>>(inp, W_ih, b_ih, b_hh, xw);
  scan_kernel<<<128, 256, 0, stream>>>(W_hh, xw, h0, g_cur, h_last, sync);
  norms_kernel<<<M_PAT / 4, 256, 0, stream>>>(patterns, bkx, bkg);
  if (use_vt) {
    vt_kernel<<<dim3(512, 8), 256, 0, stream>>>(patterns, Vt);
    flash_kernel<true><<<S * 64, 512, 0, stream>>>(g_cur, x_obs, patterns, bkx, bkg,
                                                   Vt, pacc, pml, S);
  } else {
    flash_kernel<false><<<S * 64, 512, 0, stream>>>(g_cur, x_obs, patterns, bkx, bkg,
                                                    nullptr, pacc, pml, S);
  }
  combine_kernel<<<2 * T_STEPS, 256, 0, stream>>>(pacc, pml, out, S);
}

// Round 5
// 2644.188 us; speedup vs baseline: 4.8073x; 1.2189x over previous
//
#include <hip/hip_runtime.h>
#include <math.h>

#define T_STEPS 1024
#define I_DIM   128
#define H_DIM   512
#define O_DIM   512
#define M_PAT   32768
#define SCAN_WGS 8
#define VT_STR  32800   // padded key-stride of transposed V (breaks 64KB row aliasing)

typedef __attribute__((ext_vector_type(8))) short s16x8;
typedef __attribute__((ext_vector_type(4))) float f32x4;

__device__ __forceinline__ void bf_split(float f, unsigned short& hi, unsigned short& lo) {
  unsigned u = __builtin_bit_cast(unsigned, f);
  hi = (unsigned short)(u >> 16);                       // truncation split
  float r = f - __builtin_bit_cast(float, u & 0xFFFF0000u);
  lo = (unsigned short)(__builtin_bit_cast(unsigned, r) >> 16);
}
__device__ __forceinline__ unsigned short f2bf(float f) {
  return (unsigned short)(__builtin_bit_cast(unsigned, f) >> 16);
}
__device__ __forceinline__ float bf2f(unsigned short b) {
  return __builtin_bit_cast(float, ((unsigned)b) << 16);
}

// ---------------------------------------------------------------------------
// K0: xw[t][j] = inp[t,:] . W_ih[j,:] + b_ih[j] + b_hh[j]
// ---------------------------------------------------------------------------
__global__ __launch_bounds__(256) void xw_kernel(const float* __restrict__ inp,
    const float* __restrict__ W_ih, const float* __restrict__ b_ih,
    const float* __restrict__ b_hh, float* __restrict__ xw) {
  int t = blockIdx.x;
  __shared__ float4 xs4[I_DIM / 4];
  if (threadIdx.x < I_DIM / 4)
    xs4[threadIdx.x] = ((const float4*)(inp + (size_t)t * I_DIM))[threadIdx.x];
  __syncthreads();
  for (int j = threadIdx.x; j < H_DIM; j += 256) {
    const float4* w4 = (const float4*)(W_ih + (size_t)j * I_DIM);
    float acc = 0.f;
#pragma unroll
    for (int i = 0; i < I_DIM / 4; i++) {
      float4 w = w4[i]; float4 x = xs4[i];
      acc += w.x * x.x + w.y * x.y + w.z * x.z + w.w * x.w;
    }
    xw[(size_t)t * H_DIM + j] = acc + b_ih[j] + b_hh[j];
  }
}

// ---------------------------------------------------------------------------
// K1: RNN scan, self-signaling. 128 WGs launched; 8 on one XCD elected, rest
// exit. Producers store enc = h+2.0 (range [1,3]) into henc[t] with relaxed
// agent atomics (L1-bypassing, at coherence point); consumers poll their own
// two data words with (val >= 1.0) as the ready predicate (poison 0xAA ->
// -3e-13 and memset-0 -> 0.0 both "not ready"). One LLC crossing per step
// instead of tag-flight + drain + h-load. Weights pinned in VGPRs via asm
// (round-4 VGPR_Count=100 proved the compiler was re-loading 128KB/WG/step
// of weights from L2 every iteration).
// ---------------------------------------------------------------------------
__global__ __launch_bounds__(256, 1) void scan_kernel(
    const float* __restrict__ W_hh, const float* __restrict__ xw,
    const float* __restrict__ h0, float* __restrict__ g_cur,
    float* __restrict__ h_last, unsigned* __restrict__ sync,
    unsigned* __restrict__ henc) {
  unsigned* cnt  = sync + 64;      // [8] per-xcd registration
  unsigned* dec  = sync + 128;     // decision word (0 = undecided)
  __shared__ int role_s;
  if (threadIdx.x == 0) {
    unsigned xcd = __builtin_amdgcn_s_getreg(6164) & 7u;  // HW_REG_XCC_ID
    unsigned my_idx = __hip_atomic_fetch_add(&cnt[xcd], 1u, __ATOMIC_ACQ_REL,
                                             __HIP_MEMORY_SCOPE_AGENT);
    if (blockIdx.x == 0) {
      int chosen = -1;
      while (chosen < 0) {
        for (int x = 0; x < 8; x++)
          if (__hip_atomic_load(&cnt[x], __ATOMIC_ACQUIRE,
                                __HIP_MEMORY_SCOPE_AGENT) >= 8u) { chosen = x; break; }
        if (chosen < 0) __builtin_amdgcn_s_sleep(2);
      }
      __hip_atomic_store(dec, 1u + (unsigned)chosen, __ATOMIC_RELEASE,
                         __HIP_MEMORY_SCOPE_AGENT);
    }
    unsigned d;
    while ((d = __hip_atomic_load(dec, __ATOMIC_ACQUIRE,
                                  __HIP_MEMORY_SCOPE_AGENT)) == 0u)
      __builtin_amdgcn_s_sleep(2);
    role_s = (xcd == d - 1u && my_idx < 8u) ? (int)my_idx : -1;
  }
  __syncthreads();
  const int role = role_s;
  if (role < 0) return;

  const int lane = threadIdx.x & 63;
  const int part = threadIdx.x >> 6;     // k-chunk 0..3 (128 cols each)
  const int row  = role * 64 + lane;

  float4 w[32];
  const float4* wsrc = (const float4*)(W_hh + (size_t)row * H_DIM + part * 128);
#pragma unroll
  for (int i = 0; i < 32; i++) w[i] = wsrc[i];
#pragma unroll
  for (int i = 0; i < 32; i++) {
    asm volatile("" : "+v"(w[i].x), "+v"(w[i].y), "+v"(w[i].z), "+v"(w[i].w));
  }

  __shared__ float h_sf[H_DIM];
  __shared__ float red[4][64];

  float xw_next = xw[row];               // xw[0*H + row]

  for (int t = 0; t < T_STEPS; t++) {
    float xwv = xw_next;
    if (part == 0 && t + 1 < T_STEPS)
      xw_next = xw[(size_t)(t + 1) * H_DIM + row];   // prefetch, hides HBM lat

    if (t == 0) {
      h_sf[threadIdx.x]       = h0[threadIdx.x];
      h_sf[256 + threadIdx.x] = h0[256 + threadIdx.x];
    } else {
      const unsigned* src = henc + (size_t)(t - 1) * H_DIM;
      unsigned v0, v1;
      do {
        v0 = __hip_atomic_load(src + threadIdx.x, __ATOMIC_RELAXED,
                               __HIP_MEMORY_SCOPE_AGENT);
      } while (__builtin_bit_cast(float, v0) < 1.0f);
      do {
        v1 = __hip_atomic_load(src + 256 + threadIdx.x, __ATOMIC_RELAXED,
                               __HIP_MEMORY_SCOPE_AGENT);
      } while (__builtin_bit_cast(float, v1) < 1.0f);
      h_sf[threadIdx.x]       = __builtin_bit_cast(float, v0) - 2.0f;
      h_sf[256 + threadIdx.x] = __builtin_bit_cast(float, v1) - 2.0f;
    }
    __syncthreads();

    const float4* h4 = (const float4*)h_sf + part * 32;
    float a0 = 0.f, a1 = 0.f, a2 = 0.f, a3 = 0.f;
#pragma unroll
    for (int i = 0; i < 8; i++) {
      float4 x0 = h4[4 * i], x1 = h4[4 * i + 1], x2 = h4[4 * i + 2], x3 = h4[4 * i + 3];
      float4 w0 = w[4 * i], w1 = w[4 * i + 1], w2 = w[4 * i + 2], w3 = w[4 * i + 3];
      a0 += x0.x * w0.x + x0.y * w0.y + x0.z * w0.z + x0.w * w0.w;
      a1 += x1.x * w1.x + x1.y * w1.y + x1.z * w1.z + x1.w * w1.w;
      a2 += x2.x * w2.x + x2.y * w2.y + x2.z * w2.z + x2.w * w2.w;
      a3 += x3.x * w3.x + x3.y * w3.y + x3.z * w3.z + x3.w * w3.w;
    }
    red[part][lane] = (a0 + a1) + (a2 + a3);
    __syncthreads();

    if (part == 0) {
      float pre = red[0][lane] + red[1][lane] + red[2][lane] + red[3][lane] + xwv;
      float e = __expf(2.f * pre);
      float h = 1.f - 2.f / (e + 1.f);
      // self-signaling store first (critical path), then plain output stores
      __hip_atomic_store(henc + (size_t)t * H_DIM + row,
                         __builtin_bit_cast(unsigned, h + 2.0f),
                         __ATOMIC_RELAXED, __HIP_MEMORY_SCOPE_AGENT);
      g_cur[(size_t)t * H_DIM + row] = h;
      if (t == T_STEPS - 1) h_last[row] = h;
    }
  }
}

// ---------------------------------------------------------------------------
// K2: key norms. bkx[m] = 8*||x_vals[m]||^2, bkg[m] = 8*||g_keys[m]||^2
// ---------------------------------------------------------------------------
__global__ __launch_bounds__(256) void norms_kernel(const float* __restrict__ patterns,
    float* __restrict__ bkx, float* __restrict__ bkg) {
  int lane = threadIdx.x & 63;
  int m = blockIdx.x * 4 + (threadIdx.x >> 6);
  const float4* row = (const float4*)(patterns + (size_t)m * (O_DIM + H_DIM));
  float ax = 0.f, ag = 0.f;
#pragma unroll
  for (int jj = 0; jj < 4; jj++) {
    float4 v = row[lane + 64 * jj];
    float s = v.x * v.x + v.y * v.y + v.z * v.z + v.w * v.w;
    if (jj < 2) ax += s; else ag += s;
  }
#pragma unroll
  for (int off = 1; off < 64; off <<= 1) {
    ax += __shfl_xor(ax, off, 64);
    ag += __shfl_xor(ag, off, 64);
  }
  if (lane == 0) { bkx[m] = 8.f * ax; bkg[m] = 8.f * ag; }
}

// ---------------------------------------------------------------------------
// K3: transpose x_vals -> Vt[vd][key] bf16 (trunc), padded stride VT_STR.
// ---------------------------------------------------------------------------
__global__ __launch_bounds__(256) void vt_kernel(const float* __restrict__ patterns,
                                                 unsigned short* __restrict__ Vt) {
  __shared__ unsigned short tile[64 * 68];
  int kt = blockIdx.x;   // key tile (64 keys)
  int vt = blockIdx.y;   // vd tile  (64 dims)
#pragma unroll
  for (int i = 0; i < 4; i++) {
    int f = threadIdx.x + 256 * i;        // 0..1023 : 64 keys x 16 float4
    int key = f >> 4, c4 = f & 15;
    float4 v = *(const float4*)(patterns + (size_t)(kt * 64 + key) * 1024 + vt * 64 + c4 * 4);
    unsigned short* dst = &tile[key * 68 + c4 * 4];
    dst[0] = f2bf(v.x); dst[1] = f2bf(v.y); dst[2] = f2bf(v.z); dst[3] = f2bf(v.w);
  }
  __syncthreads();
  int vd = threadIdx.x >> 2, q4 = threadIdx.x & 3;
  unsigned short tmp[16];
#pragma unroll
  for (int k = 0; k < 16; k++) tmp[k] = tile[(q4 * 16 + k) * 68 + vd];
  size_t ob = (size_t)(vt * 64 + vd) * VT_STR + kt * 64 + q4 * 16;
#pragma unroll
  for (int h = 0; h < 2; h++) {
    s16x8 pk;
#pragma unroll
    for (int j = 0; j < 8; j++) pk[j] = (short)tmp[h * 8 + j];
    *(s16x8*)&Vt[ob + h * 8] = pk;
  }
}

// ---------------------------------------------------------------------------
// K4: MFMA flash retrieval. logits = 16*(q.k) - 8*||k||^2, online softmax,
// split-bf16 QK (hi*hi + hi*lo + lo*hi), bf16 P & V for PV.
// ---------------------------------------------------------------------------
template <bool USE_VT>
__global__ __launch_bounds__(512, 2) void flash_kernel(
    const float* __restrict__ Qg, const float* __restrict__ Qx,
    const float* __restrict__ patterns, const float* __restrict__ bkx,
    const float* __restrict__ bkg, const unsigned short* __restrict__ Vt,
    float* __restrict__ pacc, float* __restrict__ pml, int S) {
  const int bid  = blockIdx.x;
  const int sidx = bid >> 6;            // key-split slow for L2 grouping
  const int ret  = (bid >> 5) & 1;
  const int qt   = bid & 31;
  const int qbase = qt * 32;

  const float* Qp  = ret ? Qx : Qg;
  const float* Kp  = patterns + (ret ? 0 : O_DIM);   // key cols
  const float* bkk = ret ? bkx : bkg;

  const int chunk = M_PAT / S;
  const int kbeg = sidx * chunk, kend = kbeg + chunk;

  const int lane = threadIdx.x & 63;
  const int wid  = threadIdx.x >> 6;    // 0..7
  const int qg   = wid >> 2;            // query group
  const int kw   = wid & 3;             // key sub-block / vd slice
  const int quad = lane >> 4;
  const int l16  = lane & 15;

  __shared__ unsigned short stage_u16[16384];       // 32 KB: khi / klo; aliases S_f
  __shared__ unsigned short p_lds[32 * 72];         // P bf16, padded stride 72
  __shared__ float mrow_s[32], lrow_s[32], alpha_s[32];
  __shared__ int flag_s;

  // ---- load Q fragments (A-layout: m=l16, k=quad*8+j), split hi/lo ----
  const int qrow = qbase + qg * 16 + l16;
  s16x8 qhi[16], qlo[16];
#pragma unroll
  for (int kst = 0; kst < 16; kst++) {
    const float4* src = (const float4*)(Qp + (size_t)qrow * 512 + kst * 32 + quad * 8);
    float4 a = src[0], b = src[1];
    float fv[8] = {a.x, a.y, a.z, a.w, b.x, b.y, b.z, b.w};
    s16x8 h, l;
#pragma unroll
    for (int j = 0; j < 8; j++) {
      unsigned short hb, lb; bf_split(fv[j], hb, lb);
      h[j] = (short)hb; l[j] = (short)lb;
    }
    qhi[kst] = h; qlo[kst] = l;
  }

  if (threadIdx.x < 32) { mrow_s[threadIdx.x] = -INFINITY; lrow_s[threadIdx.x] = 0.f; }

  f32x4 o[8];
#pragma unroll
  for (int nb = 0; nb < 8; nb++) o[nb] = (f32x4){0.f, 0.f, 0.f, 0.f};
  float ov[32];
  if (!USE_VT) {
#pragma unroll
    for (int j = 0; j < 32; j++) ov[j] = 0.f;
  }
  const int row2 = threadIdx.x >> 4;   // 0..31 (phase-2 / VALU-PV row)
  const int c0   = threadIdx.x & 15;

  for (int k0 = kbeg; k0 < kend; k0 += 64) {
    // ---------------- phase 1: scores ----------------
    f32x4 sc = (f32x4){0.f, 0.f, 0.f, 0.f};
#pragma unroll
    for (int dc = 0; dc < 4; dc++) {
      __syncthreads();                       // stage buffer free (prev reads done)
      if (dc == 0 && threadIdx.x == 0) flag_s = 0;
#pragma unroll
      for (int i = 0; i < 2; i++) {
        int oid = threadIdx.x + 512 * i;     // 1024 octets: key*16 + oct
        int key = oid >> 4, oct = oid & 15;
        const float4* src = (const float4*)(Kp + (size_t)(k0 + key) * 1024 + dc * 128 + oct * 8);
        float4 a = src[0], b = src[1];
        float fv[8] = {a.x, a.y, a.z, a.w, b.x, b.y, b.z, b.w};
        s16x8 hv, lv;
#pragma unroll
        for (int j = 0; j < 8; j++) {
          unsigned short hb, lb; bf_split(fv[j], hb, lb);
          hv[j] = (short)hb; lv[j] = (short)lb;
        }
        int base = (key * 16 + (oct ^ (key & 7))) * 8;
        *(s16x8*)&stage_u16[base] = hv;
        *(s16x8*)&stage_u16[8192 + base] = lv;
      }
      __syncthreads();
#pragma unroll
      for (int ks = 0; ks < 4; ks++) {
        int kst = dc * 4 + ks;
        int key = kw * 16 + l16;
        int oct = ks * 4 + quad;
        int base = (key * 16 + (oct ^ (key & 7))) * 8;
        s16x8 kh = *(const s16x8*)&stage_u16[base];
        s16x8 kl = *(const s16x8*)&stage_u16[8192 + base];
        sc = __builtin_amdgcn_mfma_f32_16x16x32_bf16(qhi[kst], kh, sc, 0, 0, 0);
        sc = __builtin_amdgcn_mfma_f32_16x16x32_bf16(qlo[kst], kh, sc, 0, 0, 0);
        sc = __builtin_amdgcn_mfma_f32_16x16x32_bf16(qhi[kst], kl, sc, 0, 0, 0);
      }
    }
    float bkv = bkk[k0 + kw * 16 + l16];
    __syncthreads();                         // all K reads done; stage aliases S_f now
    float* S_f = (float*)stage_u16;          // [32][68]
#pragma unroll
    for (int r = 0; r < 4; r++)
      S_f[(qg * 16 + quad * 4 + r) * 68 + kw * 16 + l16] = 16.f * sc[r] - bkv;
    __syncthreads();

    // ---------------- phase 2: online softmax ----------------
    float s4[4], p4[4];
#pragma unroll
    for (int c = 0; c < 4; c++) s4[c] = S_f[row2 * 68 + c0 + 16 * c];
    float tmax = fmaxf(fmaxf(s4[0], s4[1]), fmaxf(s4[2], s4[3]));
#pragma unroll
    for (int off = 1; off < 16; off <<= 1) tmax = fmaxf(tmax, __shfl_xor(tmax, off, 16));
    float mold = mrow_s[row2];
    float mnew = fmaxf(mold, tmax);
    float tsum = 0.f;
#pragma unroll
    for (int c = 0; c < 4; c++) { p4[c] = __expf(s4[c] - mnew); tsum += p4[c]; }
#pragma unroll
    for (int off = 1; off < 16; off <<= 1) tsum += __shfl_xor(tsum, off, 16);
#pragma unroll
    for (int c = 0; c < 4; c++) p_lds[row2 * 72 + c0 + 16 * c] = f2bf(p4[c]);
    if (c0 == 0) {
      float al = __expf(mold - mnew);
      alpha_s[row2] = al;
      mrow_s[row2] = mnew;
      lrow_s[row2] = lrow_s[row2] * al + tsum;
      if (tmax > mold - 25.f) flag_s = 1;
    }
    __syncthreads();
    const int doPV = flag_s;

    // ---------------- phase 3: PV ----------------
    if (doPV) {
      if (USE_VT) {
        float alr[4];
#pragma unroll
        for (int r = 0; r < 4; r++) alr[r] = alpha_s[qg * 16 + quad * 4 + r];
#pragma unroll
        for (int nb = 0; nb < 8; nb++) {
          o[nb][0] *= alr[0]; o[nb][1] *= alr[1]; o[nb][2] *= alr[2]; o[nb][3] *= alr[3];
        }
#pragma unroll
        for (int ks2 = 0; ks2 < 2; ks2++) {
          s16x8 pf = *(const s16x8*)&p_lds[(qg * 16 + l16) * 72 + ks2 * 32 + quad * 8];
#pragma unroll
          for (int nb = 0; nb < 8; nb++) {
            int vd = kw * 128 + nb * 16 + l16;
            s16x8 vf = *(const s16x8*)(Vt + (size_t)vd * VT_STR + (k0 + ks2 * 32 + quad * 8));
            o[nb] = __builtin_amdgcn_mfma_f32_16x16x32_bf16(pf, vf, o[nb], 0, 0, 0);
          }
        }
      } else {
        float al = alpha_s[row2];
#pragma unroll
        for (int j = 0; j < 32; j++) ov[j] *= al;
        for (int key = 0; key < 64; key++) {
          float w = bf2f(p_lds[row2 * 72 + key]);
          const float4* vsrc = (const float4*)(patterns + (size_t)(k0 + key) * 1024 + c0 * 32);
#pragma unroll
          for (int j = 0; j < 8; j++) {
            float4 v = vsrc[j];
            ov[4 * j + 0] += w * v.x; ov[4 * j + 1] += w * v.y;
            ov[4 * j + 2] += w * v.z; ov[4 * j + 3] += w * v.w;
          }
        }
      }
    }
  }

  // ---------------- epilogue: unnormalized partials + (m,l) ----------------
  __syncthreads();
  size_t pbase = ((size_t)(ret * S + sidx) * T_STEPS + qbase);
  if (USE_VT) {
#pragma unroll
    for (int nb = 0; nb < 8; nb++)
#pragma unroll
      for (int r = 0; r < 4; r++)
        pacc[(pbase + qg * 16 + quad * 4 + r) * 512 + kw * 128 + nb * 16 + l16] = o[nb][r];
  } else {
#pragma unroll
    for (int j = 0; j < 32; j++)
      pacc[(pbase + row2) * 512 + c0 * 32 + j] = ov[j];
  }
  if (threadIdx.x < 32) {
    pml[(pbase + threadIdx.x) * 2]     = mrow_s[threadIdx.x];
    pml[(pbase + threadIdx.x) * 2 + 1] = lrow_s[threadIdx.x];
  }
}

// ---------------------------------------------------------------------------
// K5: combine key-split partials -> prob_g / prob_x
// ---------------------------------------------------------------------------
__global__ __launch_bounds__(256) void combine_kernel(
    const float* __restrict__ pacc, const float* __restrict__ pml,
    float* __restrict__ out, int S) {
  int b = blockIdx.x;              // ret*1024 + r
  int ret = b >> 10, r = b & 1023;
  float M = -INFINITY;
  for (int s = 0; s < S; s++)
    M = fmaxf(M, pml[((size_t)(ret * S + s) * T_STEPS + r) * 2]);
  float L = 0.f;
  for (int s = 0; s < S; s++) {
    size_t mb = ((size_t)(ret * S + s) * T_STEPS + r) * 2;
    L += pml[mb + 1] * __expf(pml[mb] - M);
  }
  float inv = 1.0f / L;
  for (int cc = threadIdx.x; cc < 512; cc += 256) {
    float acc = 0.f;
    for (int s = 0; s < S; s++) {
      size_t mb = ((size_t)(ret * S + s) * T_STEPS + r) * 2;
      float sc = __expf(pml[mb] - M);
      acc += sc * pacc[((size_t)(ret * S + s) * T_STEPS + r) * 512 + cc];
    }
    out[(size_t)ret * (T_STEPS * O_DIM) + (size_t)r * 512 + cc] = acc * inv;
  }
}

// ---------------------------------------------------------------------------
extern "C" void kernel_launch(void* const* d_in, const int* in_sizes, int n_in,
                              void* d_out, int out_size, void* d_ws, size_t ws_size,
                              hipStream_t stream) {
  const float* inp      = (const float*)d_in[0];
  const float* x_obs    = (const float*)d_in[1];
  const float* patterns = (const float*)d_in[2];
  const float* h0       = (const float*)d_in[3];
  const float* W_ih     = (const float*)d_in[4];
  const float* W_hh     = (const float*)d_in[5];
  const float* b_ih     = (const float*)d_in[6];
  const float* b_hh     = (const float*)d_in[7];

  float* out    = (float*)d_out;
  float* g_cur  = out + 1048576;               // 1024*512
  float* h_last = out + 1572864;               // 512

  char* wsb = (char*)d_ws;
  size_t off = 0;
  auto alloc = [&](size_t bytes) -> char* {
    char* p = wsb + off; off += (bytes + 255) & ~(size_t)255; return p;
  };
  unsigned* sync = (unsigned*)alloc(8192);
  unsigned* henc = (unsigned*)alloc((size_t)T_STEPS * H_DIM * 4);   // 2 MB
  float* xw  = (float*)alloc((size_t)T_STEPS * H_DIM * 4);
  float* bkx = (float*)alloc((size_t)M_PAT * 4);
  float* bkg = (float*)alloc((size_t)M_PAT * 4);
  size_t base = off;

  const size_t vt_bytes = (size_t)512 * VT_STR * 2;
  auto pml_bytes  = [](int S) { return (size_t)2 * S * T_STEPS * 2 * 4; };
  auto pacc_bytes = [](int S) { return (size_t)2 * S * T_STEPS * 512 * 4; };

  int S = 4; bool use_vt = false;
  if (base + pml_bytes(4) + pacc_bytes(4) + vt_bytes + 1024 <= ws_size) { S = 4; use_vt = true; }
  else if (base + pml_bytes(2) + pacc_bytes(2) + vt_bytes + 1024 <= ws_size) { S = 2; use_vt = true; }
  else if (base + pml_bytes(4) + pacc_bytes(4) + 1024 <= ws_size) { S = 4; use_vt = false; }
  else if (base + pml_bytes(2) + pacc_bytes(2) + 1024 <= ws_size) { S = 2; use_vt = false; }
  else { S = 1; use_vt = false; }

  float* pml  = (float*)alloc(pml_bytes(S));
  float* pacc = (float*)alloc(pacc_bytes(S));
  unsigned short* Vt = use_vt ? (unsigned short*)alloc(vt_bytes) : (unsigned short*)nullptr;

  hipMemsetAsync(sync, 0, 8192, stream);
  hipMemsetAsync(henc, 0, (size_t)T_STEPS * H_DIM * 4, stream);
  xw_kernel<<<T_STEPS, 256, 0, stream>>>(inp, W_ih, b_ih, b_hh, xw);
  scan_kernel<<<128, 256, 0, stream>>>(W_hh, xw, h0, g_cur, h_last, sync, henc);
  norms_kernel<<<M_PAT / 4, 256, 0, stream>>>(patterns, bkx, bkg);
  if (use_vt) {
    vt_kernel<<<dim3(512, 8), 256, 0, stream>>>(patterns, Vt);
    flash_kernel<true><<<S * 64, 512, 0, stream>>>(g_cur, x_obs, patterns, bkx, bkg,
                                                   Vt, pacc, pml, S);
  } else {
    flash_kernel<false><<<S * 64, 512, 0, stream>>>(g_cur, x_obs, patterns, bkx, bkg,
                                                    nullptr, pacc, pml, S);
  }
  combine_kernel<<<2 * T_STEPS, 256, 0, stream>>>(pacc, pml, out, S);
}